// Round 2
// 441.156 us; speedup vs baseline: 1.0330x; 1.0330x over previous
//
#include <hip/hip_runtime.h>
#include <math.h>
#include <stdint.h>

#define BB 32
#define TT 4096
#define DD 512
#define UU 256

#define KC 32          // k-chunk
#define NKC (DD/KC)    // 16
#define LDA 40         // As row stride in bf16 (80 B: 20-bank stride, 2-way only)
#define NTILE (TT/64)  // 64 t-tiles per batch

typedef __attribute__((ext_vector_type(8))) short short8;
typedef __attribute__((ext_vector_type(8))) unsigned short ushort8;
typedef __attribute__((ext_vector_type(4))) float floatx4;

__device__ __forceinline__ unsigned short bf16_rne(float x) {
  union { float f; uint32_t u; } v; v.f = x;
  uint32_t r = v.u + 0x7FFFu + ((v.u >> 16) & 1u);
  return (unsigned short)(r >> 16);
}
__device__ __forceinline__ float tanh_fast(float x) {
  float e = __expf(2.0f * x);
  return 1.0f - 2.0f * __builtin_amdgcn_rcpf(e + 1.0f);
}

// lgkm-only barrier: orders LDS writes/reads across waves WITHOUT draining
// vmcnt, so global prefetches (A: HBM dist-2, B: L2 dist-1) stay in flight
// across it. Pattern proven in the 8-phase GEMM template (m194-m201):
// inline-asm counted wait + compiler-visible convergent barrier builtin.
// Safety: (1) ds_writes of chunk kc drain at barrier kc before any reader;
// (2) ds_reads of buffer b at chunk kc drain (lgkmcnt(0)) at barrier kc+1,
// before any wave can rewrite buffer b at chunk kc+2 — WAR safe.
#define BAR_LDS()                                     \
  do {                                                \
    asm volatile("s_waitcnt lgkmcnt(0)" ::: "memory");\
    __builtin_amdgcn_s_barrier();                     \
  } while (0)

// ---------------------------------------------------------------------------
// Fused setup: blocks 0..15 transpose W1 -> bf16 chunk-major w1t;
// blocks 16..47 compute hq[b][u] = query[b]@W2[:,u] + b2[u] + b1[u].
__global__ __launch_bounds__(256) void setup_kernel(
    const float* __restrict__ W1, unsigned short* __restrict__ w1t,
    const float* __restrict__ query, const float* __restrict__ W2,
    const float* __restrict__ b2, const float* __restrict__ b1,
    float* __restrict__ hq) {
  __shared__ float qs[DD];
  if (blockIdx.x < NKC) {
    const int kc = blockIdx.x;   // 0..15
    const int u = threadIdx.x;   // 0..255
    __attribute__((aligned(16))) unsigned short row[KC];
#pragma unroll
    for (int kk = 0; kk < KC; ++kk)
      row[kk] = bf16_rne(W1[(kc * KC + kk) * UU + u]);
    unsigned short* dst = w1t + ((size_t)kc * UU + u) * KC;
#pragma unroll
    for (int i = 0; i < 4; ++i) ((uint4*)dst)[i] = *(const uint4*)&row[i * 8];
  } else {
    const int b = blockIdx.x - NKC;
    const int u = threadIdx.x;
    for (int d = threadIdx.x; d < DD; d += 256) qs[d] = query[b * DD + d];
    __syncthreads();
    // 4 independent accumulator chains: breaks the 512-long serial FMA dep
    float a0 = 0.f, a1 = 0.f, a2 = 0.f, a3 = 0.f;
#pragma unroll 4
    for (int d = 0; d < DD; d += 4) {
      a0 += qs[d + 0] * W2[(d + 0) * UU + u];
      a1 += qs[d + 1] * W2[(d + 1) * UU + u];
      a2 += qs[d + 2] * W2[(d + 2) * UU + u];
      a3 += qs[d + 3] * W2[(d + 3) * UU + u];
    }
    hq[b * UU + u] = (a0 + a1) + (a2 + a3) + b2[u] + b1[u];
  }
}

// ---------------------------------------------------------------------------
// Fused: raw scores + block-local softmax partials (m_b, l_b, pctx_b[512]).
// Block: 64 t x 256 u, 4 waves. Fully-unrolled K loop (all reg indices
// compile-time), lgkm-only barrier per chunk, A reg-prefetch distance 2 (HBM),
// B-fragment reg-prefetch distance 1 (L2-hot w1t).
__global__ __launch_bounds__(256) void score_kernel(
    const float* __restrict__ values, const unsigned short* __restrict__ w1t,
    const float* __restrict__ hq, const float* __restrict__ V,
    const float* __restrict__ bV, float* __restrict__ scores,
    float* __restrict__ pml, float* __restrict__ pctx) {
  const int b = blockIdx.y;
  const int blk = blockIdx.x;
  const int t0 = blk * 64;
  const int tid = threadIdx.x;
  const int wave = tid >> 6;
  const int lane = tid & 63;
  const int c = lane & 15;   // mfma col / A-row select
  const int q = lane >> 4;   // quad: k-phase q*8, C-rows q*4..q*4+3

  __shared__ unsigned short As[2][64 * LDA];  // dbuf values tile bf16 [t][k]
  __shared__ float redW[4][64];               // per-wave score partials
  __shared__ float warr[64];                  // block-local softmax weights

  floatx4 acc[4][4];
#pragma unroll
  for (int ti = 0; ti < 4; ++ti)
#pragma unroll
    for (int ui = 0; ui < 4; ++ui) acc[ti][ui] = (floatx4){0.f, 0.f, 0.f, 0.f};

  const int ar = tid >> 2;   // A-stage row 0..63
  const int aseg = tid & 3;  // 8-float segment
  const float* asrc =
      values + ((size_t)b * TT + t0 + ar) * DD + aseg * 8;

  // B-fragment base for this lane (16 B contiguous per fragment)
  const unsigned short* bbase = w1t + ((size_t)(wave * 64 + c)) * KC + q * 8;

  // register pipeline state (all indices compile-time via full unroll)
  float4 aq[2][2];    // A fp32, chunk parity, distance 2
  short8 bfr[2][4];   // B bf16 fragments, chunk parity, distance 1

  aq[0][0] = *(const float4*)(asrc);
  aq[0][1] = *(const float4*)(asrc + 4);
  aq[1][0] = *(const float4*)(asrc + KC);
  aq[1][1] = *(const float4*)(asrc + KC + 4);
#pragma unroll
  for (int ui = 0; ui < 4; ++ui)
    bfr[0][ui] = *(const short8*)(bbase + (size_t)(ui * 16) * KC);

#pragma unroll
  for (int kc = 0; kc < NKC; ++kc) {
    const int buf = kc & 1;
    // stage chunk kc from registers into As[buf] (readers of As[buf] for
    // chunk kc-2 drained at barrier kc-1)
    {
      const float4 f0 = aq[buf][0], f1 = aq[buf][1];
      ushort8 t8;
      t8[0] = bf16_rne(f0.x); t8[1] = bf16_rne(f0.y);
      t8[2] = bf16_rne(f0.z); t8[3] = bf16_rne(f0.w);
      t8[4] = bf16_rne(f1.x); t8[5] = bf16_rne(f1.y);
      t8[6] = bf16_rne(f1.z); t8[7] = bf16_rne(f1.w);
      *(ushort8*)&As[buf][ar * LDA + aseg * 8] = t8;
    }
    // HBM prefetch of chunk kc+2 into the slot just consumed; stays in
    // flight across the lgkm-only barrier below
    if (kc + 2 < NKC) {
      aq[buf][0] = *(const float4*)(asrc + (kc + 2) * KC);
      aq[buf][1] = *(const float4*)(asrc + (kc + 2) * KC + 4);
    }
    BAR_LDS();
    // A fragments from LDS
    short8 afr[4];
#pragma unroll
    for (int ti = 0; ti < 4; ++ti)
      afr[ti] = *(const short8*)&As[buf][(ti * 16 + c) * LDA + q * 8];
    // L2 prefetch of next chunk's B fragments (consumed next iteration)
    if (kc + 1 < NKC) {
#pragma unroll
      for (int ui = 0; ui < 4; ++ui)
        bfr[buf ^ 1][ui] =
            *(const short8*)(bbase + ((size_t)(kc + 1) * UU + ui * 16) * KC);
    }
#pragma unroll
    for (int ti = 0; ti < 4; ++ti)
#pragma unroll
      for (int ui = 0; ui < 4; ++ui)
        acc[ti][ui] = __builtin_amdgcn_mfma_f32_16x16x32_bf16(
            afr[ti], bfr[buf][ui], acc[ti][ui], 0, 0, 0);
  }

  // epilogue: e = tanh(h + hq[u]) * V[u]; butterfly over 16-lane c-group
  float hqv[4], vv[4];
#pragma unroll
  for (int ui = 0; ui < 4; ++ui) {
    const int u = wave * 64 + ui * 16 + c;
    hqv[ui] = hq[b * UU + u];
    vv[ui] = V[u];
  }
#pragma unroll
  for (int ti = 0; ti < 4; ++ti)
#pragma unroll
    for (int r = 0; r < 4; ++r) {
      float e = 0.0f;
#pragma unroll
      for (int ui = 0; ui < 4; ++ui)
        e += tanh_fast(acc[ti][ui][r] + hqv[ui]) * vv[ui];
      e += __shfl_xor(e, 1, 64);
      e += __shfl_xor(e, 2, 64);
      e += __shfl_xor(e, 4, 64);
      e += __shfl_xor(e, 8, 64);
      if (c == 0) redW[wave][ti * 16 + q * 4 + r] = e;
    }
  __syncthreads();
  if (tid < 64) {
    const float s =
        bV[0] + redW[0][tid] + redW[1][tid] + redW[2][tid] + redW[3][tid];
    scores[b * TT + t0 + tid] = s;
    redW[0][tid] = s;
  }
  __syncthreads();
  float mb = -1e30f;
#pragma unroll 8
  for (int t = 0; t < 64; ++t) mb = fmaxf(mb, redW[0][t]);
  if (tid < 64) warr[tid] = __expf(redW[0][tid] - mb);
  __syncthreads();
  float lb = 0.0f;
#pragma unroll 8
  for (int t = 0; t < 64; ++t) lb += warr[t];

  // partial context: thread owns float2 at d = 2*tid; values tile is L2-hot
  const float2* vp = (const float2*)(values + ((size_t)b * TT + t0) * DD);
  float2 c2 = {0.f, 0.f};
#pragma unroll 4
  for (int t = 0; t < 64; ++t) {
    const float w = warr[t];
    const float2 v = vp[(size_t)t * (DD / 2) + tid];
    c2.x += w * v.x;
    c2.y += w * v.y;
  }
  *(float2*)&pctx[((size_t)b * NTILE + blk) * DD + 2 * tid] = c2;
  if (tid == 0) {
    pml[(b * NTILE + blk) * 2 + 0] = mb;
    pml[(b * NTILE + blk) * 2 + 1] = lb;
  }
}

// ---------------------------------------------------------------------------
// Fused combine + weights: per b, global m/l from 64 tile-partials,
// rescale+sum pctx -> context out, then write normalized weights (scores
// are L2-hot from score_kernel). Drops the stats round-trip + one launch.
__global__ __launch_bounds__(256) void combine_kernel(
    const float* __restrict__ pml, const float* __restrict__ pctx,
    const float* __restrict__ scores, float* __restrict__ out) {
  const int b = blockIdx.x;
  const int tid = threadIdx.x;
  __shared__ float mls[2 * NTILE];
  __shared__ float cs[NTILE];
  if (tid < 2 * NTILE) mls[tid] = pml[b * 2 * NTILE + tid];
  __syncthreads();
  float m = -1e30f;
#pragma unroll 8
  for (int i = 0; i < NTILE; ++i) m = fmaxf(m, mls[2 * i]);
  if (tid < NTILE) cs[tid] = __expf(mls[2 * tid] - m);
  __syncthreads();
  float l = 0.0f;
#pragma unroll 8
  for (int i = 0; i < NTILE; ++i) l += cs[i] * mls[2 * i + 1];
  const float linv = 1.0f / l;

  const float2* pp = (const float2*)(pctx + (size_t)b * NTILE * DD);
  float2 acc = {0.f, 0.f};
#pragma unroll 4
  for (int i = 0; i < NTILE; ++i) {
    const float cw = cs[i];
    const float2 p = pp[(size_t)i * (DD / 2) + tid];
    acc.x += cw * p.x;
    acc.y += cw * p.y;
  }
  out[b * DD + 2 * tid + 0] = acc.x * linv;
  out[b * DD + 2 * tid + 1] = acc.y * linv;

  // weights[b,t] = exp(scores[b,t] - m) / l
  float* wout = out + BB * DD + (size_t)b * TT;
  const float* srow = scores + (size_t)b * TT;
#pragma unroll
  for (int i = 0; i < TT / 256; ++i) {
    const int t = i * 256 + tid;
    wout[t] = __expf(srow[t] - m) * linv;
  }
}

// ---------------------------------------------------------------------------
extern "C" void kernel_launch(void* const* d_in, const int* in_sizes, int n_in,
                              void* d_out, int out_size, void* d_ws, size_t ws_size,
                              hipStream_t stream) {
  const float* values = (const float*)d_in[0];
  const float* query  = (const float*)d_in[1];
  const float* W1     = (const float*)d_in[2];
  const float* b1     = (const float*)d_in[3];
  const float* W2     = (const float*)d_in[4];
  const float* b2     = (const float*)d_in[5];
  const float* V      = (const float*)d_in[6];
  const float* bV     = (const float*)d_in[7];
  float* out = (float*)d_out;

  float* ws = (float*)d_ws;
  float* hq     = ws;                          // 32*256 floats
  float* scores = ws + BB * UU;                // 32*4096 floats
  float* pml    = scores + BB * TT;            // 32*64*2 = 4096 floats
  float* pctx   = pml + BB * NTILE * 2;        // 32*64*512 floats (4 MB)
  unsigned short* w1t = (unsigned short*)(pctx + (size_t)BB * NTILE * DD);

  setup_kernel<<<NKC + BB, 256, 0, stream>>>(W1, w1t, query, W2, b2, b1, hq);
  score_kernel<<<dim3(NTILE, BB), 256, 0, stream>>>(
      values, w1t, hq, V, bV, scores, pml, pctx);
  combine_kernel<<<BB, 256, 0, stream>>>(pml, pctx, scores, out);
}

// Round 3
// 434.577 us; speedup vs baseline: 1.0487x; 1.0151x over previous
//
#include <hip/hip_runtime.h>
#include <math.h>
#include <stdint.h>

#define BB 32
#define TT 4096
#define DD 512
#define UU 256

#define KC 32          // k-chunk (MFMA K)
#define NKC (DD/KC)    // 16 chunks
#define NST (NKC/2)    // 8 K-steps of 64 (2 chunks per barrier)
#define LDA2 72        // As row stride in bf16 (144 B): verified min-depth banks
#define NTILE (TT/64)  // 64 t-tiles per batch

typedef __attribute__((ext_vector_type(8))) short short8;
typedef __attribute__((ext_vector_type(8))) unsigned short ushort8;
typedef __attribute__((ext_vector_type(4))) float floatx4;

__device__ __forceinline__ unsigned short bf16_rne(float x) {
  union { float f; uint32_t u; } v; v.f = x;
  uint32_t r = v.u + 0x7FFFu + ((v.u >> 16) & 1u);
  return (unsigned short)(r >> 16);
}
// HW packed fp32->bf16 RNE: dst = {lo16=bf16(a), hi16=bf16(b)} (no builtin on
// gfx950 — inline asm per T12 recipe). Bit-identical to bf16_rne pairs.
__device__ __forceinline__ unsigned int cvt_pk_bf16(float a, float b) {
  unsigned int r;
  asm("v_cvt_pk_bf16_f32 %0, %1, %2" : "=v"(r) : "v"(a), "v"(b));
  return r;
}
__device__ __forceinline__ float tanh_fast(float x) {
  float e = __expf(2.0f * x);
  return 1.0f - 2.0f * __builtin_amdgcn_rcpf(e + 1.0f);
}

// lgkm-only barrier: orders LDS writes/reads across waves WITHOUT draining
// vmcnt, so global prefetches (A: HBM dist-1-step, B: L2 dist-1-step) stay in
// flight across it. Safety: (1) ds_writes of step s drain at barrier s before
// any reader; (2) ds_reads of buffer p at step s drain (lgkmcnt(0)) at
// barrier s+1, before any wave rewrites buffer p at step s+2 — WAR safe.
#define BAR_LDS()                                     \
  do {                                                \
    asm volatile("s_waitcnt lgkmcnt(0)" ::: "memory");\
    __builtin_amdgcn_s_barrier();                     \
  } while (0)

// ---------------------------------------------------------------------------
// Fused setup: blocks 0..15 transpose W1 -> bf16 chunk-major w1t;
// blocks 16..47 compute hq[b][u] = query[b]@W2[:,u] + b2[u] + b1[u].
__global__ __launch_bounds__(256) void setup_kernel(
    const float* __restrict__ W1, unsigned short* __restrict__ w1t,
    const float* __restrict__ query, const float* __restrict__ W2,
    const float* __restrict__ b2, const float* __restrict__ b1,
    float* __restrict__ hq) {
  __shared__ float qs[DD];
  if (blockIdx.x < NKC) {
    const int kc = blockIdx.x;   // 0..15
    const int u = threadIdx.x;   // 0..255
    __attribute__((aligned(16))) unsigned short row[KC];
#pragma unroll
    for (int kk = 0; kk < KC; ++kk)
      row[kk] = bf16_rne(W1[(kc * KC + kk) * UU + u]);
    unsigned short* dst = w1t + ((size_t)kc * UU + u) * KC;
#pragma unroll
    for (int i = 0; i < 4; ++i) ((uint4*)dst)[i] = *(const uint4*)&row[i * 8];
  } else {
    const int b = blockIdx.x - NKC;
    const int u = threadIdx.x;
    for (int d = threadIdx.x; d < DD; d += 256) qs[d] = query[b * DD + d];
    __syncthreads();
    // 4 independent accumulator chains: breaks the 512-long serial FMA dep
    float a0 = 0.f, a1 = 0.f, a2 = 0.f, a3 = 0.f;
#pragma unroll 4
    for (int d = 0; d < DD; d += 4) {
      a0 += qs[d + 0] * W2[(d + 0) * UU + u];
      a1 += qs[d + 1] * W2[(d + 1) * UU + u];
      a2 += qs[d + 2] * W2[(d + 2) * UU + u];
      a3 += qs[d + 3] * W2[(d + 3) * UU + u];
    }
    hq[b * UU + u] = (a0 + a1) + (a2 + a3) + b2[u] + b1[u];
  }
}

// ---------------------------------------------------------------------------
// Fused: raw scores + block-local softmax partials (m_b, l_b, pctx_b[512]).
// Block: 64 t x 256 u, 4 waves. K-steps of 64 (2 chunks): 8 barriers for
// 256 MFMAs (32 per sync point). Fully-unrolled (all reg indices
// compile-time). A reg-prefetch 1 step ahead (HBM), B-fragments 1 step ahead
// (L2-hot w1t). cvt_pk staging, setprio around MFMA clusters.
__global__ __launch_bounds__(256, 2) void score_kernel(
    const float* __restrict__ values, const unsigned short* __restrict__ w1t,
    const float* __restrict__ hq, const float* __restrict__ V,
    const float* __restrict__ bV, float* __restrict__ scores,
    float* __restrict__ pml, float* __restrict__ pctx) {
  const int b = blockIdx.y;
  const int blk = blockIdx.x;
  const int t0 = blk * 64;
  const int tid = threadIdx.x;
  const int wave = tid >> 6;
  const int lane = tid & 63;
  const int c = lane & 15;   // mfma col / A-row select
  const int q = lane >> 4;   // quad: k-phase q*8, C-rows q*4..q*4+3

  __shared__ unsigned short As[2][64 * LDA2];  // dbuf values tile bf16 [t][k64]
  __shared__ float redW[4][64];                // per-wave score partials
  __shared__ float warr[64];                   // block-local softmax weights

  floatx4 acc[4][4];
#pragma unroll
  for (int ti = 0; ti < 4; ++ti)
#pragma unroll
    for (int ui = 0; ui < 4; ++ui) acc[ti][ui] = (floatx4){0.f, 0.f, 0.f, 0.f};

  const int ar = tid >> 2;   // A-stage row 0..63
  const int aseg = tid & 3;  // 8-float segment within a 32-float chunk
  const float* asrc =
      values + ((size_t)b * TT + t0 + ar) * DD + aseg * 8;

  // B-fragment base for this lane (16 B contiguous per fragment)
  const unsigned short* bbase = w1t + ((size_t)(wave * 64 + c)) * KC + q * 8;

  // register pipeline state (all indices compile-time via full unroll)
  float4 aq[2][4];    // A fp32: [step parity][chunk0 f4x2, chunk1 f4x2]
  short8 bfr[2][8];   // B bf16: [step parity][chunk j2*4 + ui]

  // prologue: A steps 0,1; B step 0
#pragma unroll
  for (int j = 0; j < 2; ++j) {
    aq[0][2 * j + 0] = *(const float4*)(asrc + j * KC);
    aq[0][2 * j + 1] = *(const float4*)(asrc + j * KC + 4);
    aq[1][2 * j + 0] = *(const float4*)(asrc + (2 + j) * KC);
    aq[1][2 * j + 1] = *(const float4*)(asrc + (2 + j) * KC + 4);
  }
#pragma unroll
  for (int j = 0; j < 2; ++j)
#pragma unroll
    for (int ui = 0; ui < 4; ++ui)
      bfr[0][j * 4 + ui] =
          *(const short8*)(bbase + ((size_t)(j * UU) + ui * 16) * KC);

#pragma unroll
  for (int s = 0; s < NST; ++s) {
    const int buf = s & 1;
    // stage step s (chunks 2s, 2s+1) into As[buf] via packed cvt
    {
      uint4 w0, w1;
      w0.x = cvt_pk_bf16(aq[buf][0].x, aq[buf][0].y);
      w0.y = cvt_pk_bf16(aq[buf][0].z, aq[buf][0].w);
      w0.z = cvt_pk_bf16(aq[buf][1].x, aq[buf][1].y);
      w0.w = cvt_pk_bf16(aq[buf][1].z, aq[buf][1].w);
      w1.x = cvt_pk_bf16(aq[buf][2].x, aq[buf][2].y);
      w1.y = cvt_pk_bf16(aq[buf][2].z, aq[buf][2].w);
      w1.z = cvt_pk_bf16(aq[buf][3].x, aq[buf][3].y);
      w1.w = cvt_pk_bf16(aq[buf][3].z, aq[buf][3].w);
      *(uint4*)&As[buf][ar * LDA2 + aseg * 8] = w0;
      *(uint4*)&As[buf][ar * LDA2 + 32 + aseg * 8] = w1;
    }
    // HBM prefetch of step s+2 into the parity slot just consumed; stays in
    // flight across the lgkm-only barrier below
    if (s + 2 < NST) {
#pragma unroll
      for (int j = 0; j < 2; ++j) {
        aq[buf][2 * j + 0] = *(const float4*)(asrc + (2 * (s + 2) + j) * KC);
        aq[buf][2 * j + 1] =
            *(const float4*)(asrc + (2 * (s + 2) + j) * KC + 4);
      }
    }
    BAR_LDS();
    // L2 prefetch of next step's B fragments (consumed next iteration)
    if (s + 1 < NST) {
#pragma unroll
      for (int j = 0; j < 2; ++j)
#pragma unroll
        for (int ui = 0; ui < 4; ++ui)
          bfr[buf ^ 1][j * 4 + ui] = *(const short8*)(
              bbase + ((size_t)(2 * (s + 1) + j) * UU + ui * 16) * KC);
    }
    // chunk 0 of step
    {
      short8 afr[4];
#pragma unroll
      for (int ti = 0; ti < 4; ++ti)
        afr[ti] = *(const short8*)&As[buf][(ti * 16 + c) * LDA2 + q * 8];
      __builtin_amdgcn_s_setprio(1);
#pragma unroll
      for (int ti = 0; ti < 4; ++ti)
#pragma unroll
        for (int ui = 0; ui < 4; ++ui)
          acc[ti][ui] = __builtin_amdgcn_mfma_f32_16x16x32_bf16(
              afr[ti], bfr[buf][ui], acc[ti][ui], 0, 0, 0);
      __builtin_amdgcn_s_setprio(0);
    }
    // chunk 1 of step
    {
      short8 afr[4];
#pragma unroll
      for (int ti = 0; ti < 4; ++ti)
        afr[ti] = *(const short8*)&As[buf][(ti * 16 + c) * LDA2 + 32 + q * 8];
      __builtin_amdgcn_s_setprio(1);
#pragma unroll
      for (int ti = 0; ti < 4; ++ti)
#pragma unroll
        for (int ui = 0; ui < 4; ++ui)
          acc[ti][ui] = __builtin_amdgcn_mfma_f32_16x16x32_bf16(
              afr[ti], bfr[buf][4 + ui], acc[ti][ui], 0, 0, 0);
      __builtin_amdgcn_s_setprio(0);
    }
  }

  // epilogue: e = tanh(h + hq[u]) * V[u]; butterfly over 16-lane c-group
  float hqv[4], vv[4];
#pragma unroll
  for (int ui = 0; ui < 4; ++ui) {
    const int u = wave * 64 + ui * 16 + c;
    hqv[ui] = hq[b * UU + u];
    vv[ui] = V[u];
  }
#pragma unroll
  for (int ti = 0; ti < 4; ++ti)
#pragma unroll
    for (int r = 0; r < 4; ++r) {
      float e = 0.0f;
#pragma unroll
      for (int ui = 0; ui < 4; ++ui)
        e += tanh_fast(acc[ti][ui][r] + hqv[ui]) * vv[ui];
      e += __shfl_xor(e, 1, 64);
      e += __shfl_xor(e, 2, 64);
      e += __shfl_xor(e, 4, 64);
      e += __shfl_xor(e, 8, 64);
      if (c == 0) redW[wave][ti * 16 + q * 4 + r] = e;
    }
  __syncthreads();
  if (tid < 64) {
    const float s =
        bV[0] + redW[0][tid] + redW[1][tid] + redW[2][tid] + redW[3][tid];
    scores[b * TT + t0 + tid] = s;
    redW[0][tid] = s;
  }
  __syncthreads();
  float mb = -1e30f;
#pragma unroll 8
  for (int t = 0; t < 64; ++t) mb = fmaxf(mb, redW[0][t]);
  if (tid < 64) warr[tid] = __expf(redW[0][tid] - mb);
  __syncthreads();
  float lb = 0.0f;
#pragma unroll 8
  for (int t = 0; t < 64; ++t) lb += warr[t];

  // partial context: thread owns float2 at d = 2*tid; values tile is L2-hot
  const float2* vp = (const float2*)(values + ((size_t)b * TT + t0) * DD);
  float2 c2 = {0.f, 0.f};
#pragma unroll 4
  for (int t = 0; t < 64; ++t) {
    const float w = warr[t];
    const float2 v = vp[(size_t)t * (DD / 2) + tid];
    c2.x += w * v.x;
    c2.y += w * v.y;
  }
  *(float2*)&pctx[((size_t)b * NTILE + blk) * DD + 2 * tid] = c2;
  if (tid == 0) {
    pml[(b * NTILE + blk) * 2 + 0] = mb;
    pml[(b * NTILE + blk) * 2 + 1] = lb;
  }
}

// ---------------------------------------------------------------------------
// Fused combine + weights: per b, global m/l from 64 tile-partials,
// rescale+sum pctx -> context out, then write normalized weights (scores
// are L2-hot from score_kernel).
__global__ __launch_bounds__(256) void combine_kernel(
    const float* __restrict__ pml, const float* __restrict__ pctx,
    const float* __restrict__ scores, float* __restrict__ out) {
  const int b = blockIdx.x;
  const int tid = threadIdx.x;
  __shared__ float mls[2 * NTILE];
  __shared__ float cs[NTILE];
  if (tid < 2 * NTILE) mls[tid] = pml[b * 2 * NTILE + tid];
  __syncthreads();
  float m = -1e30f;
#pragma unroll 8
  for (int i = 0; i < NTILE; ++i) m = fmaxf(m, mls[2 * i]);
  if (tid < NTILE) cs[tid] = __expf(mls[2 * tid] - m);
  __syncthreads();
  float l = 0.0f;
#pragma unroll 8
  for (int i = 0; i < NTILE; ++i) l += cs[i] * mls[2 * i + 1];
  const float linv = 1.0f / l;

  const float2* pp = (const float2*)(pctx + (size_t)b * NTILE * DD);
  float2 acc = {0.f, 0.f};
#pragma unroll 4
  for (int i = 0; i < NTILE; ++i) {
    const float cw = cs[i];
    const float2 p = pp[(size_t)i * (DD / 2) + tid];
    acc.x += cw * p.x;
    acc.y += cw * p.y;
  }
  out[b * DD + 2 * tid + 0] = acc.x * linv;
  out[b * DD + 2 * tid + 1] = acc.y * linv;

  // weights[b,t] = exp(scores[b,t] - m) / l
  float* wout = out + BB * DD + (size_t)b * TT;
  const float* srow = scores + (size_t)b * TT;
#pragma unroll
  for (int i = 0; i < TT / 256; ++i) {
    const int t = i * 256 + tid;
    wout[t] = __expf(srow[t] - m) * linv;
  }
}

// ---------------------------------------------------------------------------
extern "C" void kernel_launch(void* const* d_in, const int* in_sizes, int n_in,
                              void* d_out, int out_size, void* d_ws, size_t ws_size,
                              hipStream_t stream) {
  const float* values = (const float*)d_in[0];
  const float* query  = (const float*)d_in[1];
  const float* W1     = (const float*)d_in[2];
  const float* b1     = (const float*)d_in[3];
  const float* W2     = (const float*)d_in[4];
  const float* b2     = (const float*)d_in[5];
  const float* V      = (const float*)d_in[6];
  const float* bV     = (const float*)d_in[7];
  float* out = (float*)d_out;

  float* ws = (float*)d_ws;
  float* hq     = ws;                          // 32*256 floats
  float* scores = ws + BB * UU;                // 32*4096 floats
  float* pml    = scores + BB * TT;            // 32*64*2 = 4096 floats
  float* pctx   = pml + BB * NTILE * 2;        // 32*64*512 floats (4 MB)
  unsigned short* w1t = (unsigned short*)(pctx + (size_t)BB * NTILE * DD);

  setup_kernel<<<NKC + BB, 256, 0, stream>>>(W1, w1t, query, W2, b2, b1, hq);
  score_kernel<<<dim3(NTILE, BB), 256, 0, stream>>>(
      values, w1t, hq, V, bV, scores, pml, pctx);
  combine_kernel<<<BB, 256, 0, stream>>>(pml, pctx, scores, out);
}